// Round 10
// baseline (247.290 us; speedup 1.0000x reference)
//
#include <hip/hip_runtime.h>
#include <cstdint>

#define B_   8
#define C_   256
#define NQ_  1024
#define NK_  4096
#define S_   16
#define H_   8
#define FF_  2048
#define DH_  32
#define BQ_  (B_*NQ_)
#define EPS_ 1e-5f

typedef __bf16 bf16x8 __attribute__((ext_vector_type(8)));
typedef __bf16 bf16x4 __attribute__((ext_vector_type(4)));
typedef float  f32x4  __attribute__((ext_vector_type(4)));

struct CvtArgs {
  const float* src[6];
  __bf16* dst[6];
};

// async global->LDS DMA, 16B per lane. LDS dest is wave-uniform base + lane*16.
__device__ __forceinline__ void gload_lds16(const void* g, void* l) {
  __builtin_amdgcn_global_load_lds(
      (const __attribute__((address_space(1))) void*)g,
      (__attribute__((address_space(3))) void*)l, 16, 0, 0);
}

// ================= k_prep: one launch for all preprocessing =================
// [0,2048) box query | [2048,6144) key transpose (64Cx32NK, full-line writes)
// [6144,8192) query transpose+qpe | [8192,9472) weight casts | [9472,9488) Pk/Pv
#define SEGA 2048
#define SEGB 6144
#define SEGC 8192
#define SEGD 9472
#define NPREP 9488

__global__ __launch_bounds__(256) void k_prep(
    const float* __restrict__ query, const float* __restrict__ key,
    const float* __restrict__ query_pos, const float* __restrict__ key_pos,
    const float* __restrict__ qpe_w, const float* __restrict__ qpe_b,
    const float* __restrict__ k_w, const float* __restrict__ k_b,
    const float* __restrict__ v_w, const float* __restrict__ v_b,
    const float* __restrict__ kpe_w, const float* __restrict__ kpe_b,
    CvtArgs ca,
    __bf16* __restrict__ keyTb, __bf16* __restrict__ qtokb,
    __bf16* __restrict__ qinb,
    float4* __restrict__ Pk, float4* __restrict__ Pv,
    int* __restrict__ idxo, int* __restrict__ masko) {
  __shared__ __align__(16) float smem[2112];
  int blk = blockIdx.x, t = threadIdx.x;
  int tx = t & 31, ty = t >> 5;

  if (blk < SEGA) {
    // ---- box query: batched 4-chunk scan ----
    int lane = t & 63;
    int q = blk * 4 + (t >> 6);
    int b = q >> 10;
    const float* kpb = key_pos + (size_t)b * NK_ * 3;
    const float* qp = query_pos + (size_t)q * 6;
    float cx = qp[0], cy = qp[1], cz = qp[2];
    float hx = 0.5f * qp[3], hy = 0.5f * qp[4], hz = 0.5f * qp[5];
    int* iq = idxo + (size_t)q * S_;
    int found = 0;
    for (int ch = 0; ch < NK_ / 64; ch += 4) {
      float dx[4], dy[4], dz[4];
#pragma unroll
      for (int u = 0; u < 4; ++u) {
        int k = (ch + u) * 64 + lane;
        dx[u] = fabsf(kpb[k * 3 + 0] - cx);
        dy[u] = fabsf(kpb[k * 3 + 1] - cy);
        dz[u] = fabsf(kpb[k * 3 + 2] - cz);
      }
#pragma unroll
      for (int u = 0; u < 4; ++u) {
        bool inside = (dx[u] <= hx) && (dy[u] <= hy) && (dz[u] <= hz);
        unsigned long long bal = __ballot(inside);
        if (inside) {
          int slot = found + __popcll(bal & ((1ull << lane) - 1ull));
          if (slot < S_) iq[slot] = (ch + u) * 64 + lane;
        }
        found += __popcll(bal);
      }
      if (found >= S_) break;
    }
    if (found > S_) found = S_;
    if (lane < S_) {
      int m = (lane < found) ? 0 : 1;
      if (lane >= found) iq[lane] = 0;
      if (lane == 0) m = 0;
      masko[(size_t)q * S_ + lane] = m;
    }
  } else if (blk < SEGB) {
    // ---- key transpose: 64C x 32NK tiles; 128B-line bf16x8 writes ----
    int local = blk - SEGA;            // 0..4095
    float (*tt)[33] = (float(*)[33])smem;   // [64][33]
    int x = local & 127;               // NK tile (128)
    int y = (local >> 7) & 3;          // C tile (4)
    int z = local >> 9;                // batch (8)
    int j0 = x * 32, i0 = y * 64;
    const float* inz = key + (size_t)z * C_ * NK_;
    __bf16* outz = keyTb + (size_t)z * NK_ * C_;
#pragma unroll
    for (int r = 0; r < 64; r += 8)
      tt[ty + r][tx] = inz[(size_t)(i0 + ty + r) * NK_ + (j0 + tx)];
    __syncthreads();
    {
      int nk = t >> 3;                 // 0..31
      int c8 = (t & 7) * 8;            // 8-col chunk base
      bf16x8 v;
#pragma unroll
      for (int u = 0; u < 8; ++u) v[u] = (__bf16)tt[c8 + u][nk];
      *(bf16x8*)&outz[(size_t)(j0 + nk) * C_ + i0 + c8] = v;
    }
  } else if (blk < SEGC) {
    // ---- query transpose + qpe (both outputs bf16) ----
    int local = blk - SEGB;
    float (*tt)[33] = (float(*)[33])smem;
    float (*sqp)[6] = (float(*)[6])(smem + 1056);
    int x = local & 31, y = (local >> 5) & 7, z = local >> 8;
    int nq0 = x * 32, c0 = y * 32;
    const float* inz = query + (size_t)z * C_ * NQ_;
#pragma unroll
    for (int r = 0; r < 32; r += 8)
      tt[ty + r][tx] = inz[(size_t)(c0 + ty + r) * NQ_ + (nq0 + tx)];
    if (t < 192)
      sqp[t / 6][t % 6] = query_pos[((size_t)z * NQ_ + nq0 + t / 6) * 6 + (t % 6)];
    int c = c0 + tx;
    float w0 = qpe_w[c * 6 + 0], w1 = qpe_w[c * 6 + 1], w2 = qpe_w[c * 6 + 2];
    float w3 = qpe_w[c * 6 + 3], w4 = qpe_w[c * 6 + 4], w5 = qpe_w[c * 6 + 5];
    float wb = qpe_b[c];
    __syncthreads();
#pragma unroll
    for (int r = 0; r < 32; r += 8) {
      int nql = ty + r;
      size_t row = (size_t)z * NQ_ + nq0 + nql;
      float v = tt[tx][nql];
      float pe = wb + sqp[nql][0] * w0 + sqp[nql][1] * w1 + sqp[nql][2] * w2 +
                 sqp[nql][3] * w3 + sqp[nql][4] * w4 + sqp[nql][5] * w5;
      qtokb[row * C_ + c] = (__bf16)v;
      qinb[row * C_ + c] = (__bf16)(v + pe);
    }
  } else if (blk < SEGD) {
    // ---- weight casts ----
    int local = blk - SEGC;
    int idx, base;
    if (local < 64)       { idx = 0; base = local; }
    else if (local < 128) { idx = 1; base = local - 64; }
    else if (local < 192) { idx = 2; base = local - 128; }
    else if (local < 256) { idx = 3; base = local - 192; }
    else if (local < 768) { idx = 4; base = local - 256; }
    else                  { idx = 5; base = local - 768; }
    size_t off = (size_t)base * 1024 + t * 4;
    float4 v = *(const float4*)(ca.src[idx] + off);
    __bf16* o = ca.dst[idx] + off;
    o[0] = (__bf16)v.x; o[1] = (__bf16)v.y; o[2] = (__bf16)v.z; o[3] = (__bf16)v.w;
  } else {
    // ---- Pk / Pv fold ----
    int local = blk - SEGD;
    int bx = local & 7, bv = local >> 3;
    const float* w  = bv ? v_w : k_w;
    const float* wb = bv ? v_b : k_b;
    float4* P = bv ? Pv : Pk;
    float4 (*red)[8] = (float4(*)[8])smem;
    int nl = t >> 3, ks = (t & 7) * 32;
    int n = bx * 32 + nl;
    const float* wr = w + (size_t)n * C_;
    float p0 = 0.f, p1 = 0.f, p2 = 0.f, pb = 0.f;
#pragma unroll
    for (int k = ks; k < ks + 32; ++k) {
      float wv = wr[k];
      p0 += kpe_w[k * 3 + 0] * wv;
      p1 += kpe_w[k * 3 + 1] * wv;
      p2 += kpe_w[k * 3 + 2] * wv;
      pb += kpe_b[k] * wv;
    }
    red[nl][t & 7] = make_float4(p0, p1, p2, pb);
    __syncthreads();
    if (t < 32) {
      float4 s = red[t][0];
#pragma unroll
      for (int j = 1; j < 8; ++j) {
        float4 r = red[t][j];
        s.x += r.x; s.y += r.y; s.z += r.z; s.w += r.w;
      }
      s.w += wb[bx * 32 + t];
      P[bx * 32 + t] = s;
    }
  }
}

// ============== core MFMA tile (4-wave, 256-thread kernels) ========
// global_load_lds(16B) into LINEAR [R][64] LDS, source-side chunk XOR-swizzle
// (chunk ^= row&7) mirrored on the ds_read side (2-way = free).
template <int BM, int BN>
__device__ __forceinline__ void gemm_tile(
    const __bf16* __restrict__ A, const __bf16* __restrict__ Wn,
    int m0, int n0, int K, int kbeg, int kend,
    __bf16 (*As)[64], __bf16 (*Bs)[64],
    f32x4 (&acc)[BM / 32][BN / 32]) {
  constexpr int MI = BM / 32, JN = BN / 32;
  constexpr int AI = BM / 32, BI = BN / 32;
  int t = threadIdx.x;
  int lane = t & 63, w = t >> 6;
  int lane16 = lane & 15, quad = lane >> 4;
  int wm = (w & 1) * (BM / 2), wn = (w >> 1) * (BN / 2);
  int l3 = lane >> 3;
  int lc = lane & 7;

  for (int k0 = kbeg; k0 < kend; k0 += 64) {
#pragma unroll
    for (int i = 0; i < AI; ++i) {
      int j = i * 4 + w;
      int row = j * 8 + l3;
      const __bf16* src = A + (size_t)(m0 + row) * K + k0 + ((lc ^ l3) << 3);
      gload_lds16(src, (char*)&As[0][0] + j * 1024);
    }
#pragma unroll
    for (int i = 0; i < BI; ++i) {
      int j = i * 4 + w;
      int row = j * 8 + l3;
      const __bf16* src = Wn + (size_t)(n0 + row) * K + k0 + ((lc ^ l3) << 3);
      gload_lds16(src, (char*)&Bs[0][0] + j * 1024);
    }
    __syncthreads();
#pragma unroll
    for (int kk = 0; kk < 64; kk += 32) {
      bf16x8 af[MI], bfr[JN];
      int qc = (kk >> 3) + quad;
#pragma unroll
      for (int i = 0; i < MI; ++i) {
        int row = wm + i * 16 + lane16;
        int ch = qc ^ (lane16 & 7);
        af[i] = *(const bf16x8*)((const char*)&As[row][0] + ch * 16);
      }
#pragma unroll
      for (int j = 0; j < JN; ++j) {
        int row = wn + j * 16 + lane16;
        int ch = qc ^ (lane16 & 7);
        bfr[j] = *(const bf16x8*)((const char*)&Bs[row][0] + ch * 16);
      }
#pragma unroll
      for (int i = 0; i < MI; ++i)
#pragma unroll
        for (int j = 0; j < JN; ++j)
          acc[i][j] = __builtin_amdgcn_mfma_f32_16x16x32_bf16(af[i], bfr[j], acc[i][j], 0, 0, 0);
    }
    __syncthreads();
  }
}

// ============== generic GEMM with LDS-staged coalesced epilogue ==============
template <int BM, int BN, int RELU, int OUT_BF16>
__device__ __forceinline__ void gemm_body(
    const __bf16* __restrict__ A, const __bf16* __restrict__ Wn,
    const float* __restrict__ bias, void* __restrict__ outp,
    int n0, int m0, int N, int K, int kbeg, int kend) {
  constexpr int MI = BM / 32, JN = BN / 32;
  __shared__ __align__(16) char smem[(BM + BN) * 128];
  __bf16 (*As)[64] = (__bf16(*)[64])smem;
  __bf16 (*Bs)[64] = (__bf16(*)[64])(smem + (size_t)BM * 128);
  int t = threadIdx.x;
  int lane = t & 63, w = t >> 6;
  int lane16 = lane & 15, quad = lane >> 4;
  int wm = (w & 1) * (BM / 2), wn = (w >> 1) * (BN / 2);

  f32x4 acc[MI][JN];
#pragma unroll
  for (int i = 0; i < MI; ++i)
#pragma unroll
    for (int j = 0; j < JN; ++j) acc[i][j] = (f32x4){0.f, 0.f, 0.f, 0.f};

  gemm_tile<BM, BN>(A, Wn, m0, n0, K, kbeg, kend, As, Bs, acc);

  if constexpr (OUT_BF16 && (BM * BN * 2 <= (BM + BN) * 128)) {
    __bf16* Cs = (__bf16*)smem;   // BM*BN bf16, aliases dead As/Bs
#pragma unroll
    for (int j = 0; j < JN; ++j) {
      int col = wn + j * 16 + lane16;
      float bv = bias ? bias[n0 + col] : 0.f;
#pragma unroll
      for (int i = 0; i < MI; ++i)
#pragma unroll
        for (int r = 0; r < 4; ++r) {
          int row = wm + i * 16 + quad * 4 + r;
          float v = acc[i][j][r] + bv;
          if (RELU) v = fmaxf(v, 0.f);
          int sw = ((col >> 3) ^ ((row >> 2) & 3)) * 8 + (col & 7);
          Cs[row * BN + sw] = (__bf16)v;
        }
    }
    __syncthreads();
    constexpr int PASSES = BM * BN * 2 / (256 * 16);
#pragma unroll
    for (int p = 0; p < PASSES; ++p) {
      int off = p * 4096 + t * 16;          // byte offset within C tile
      int row = off / (BN * 2);
      int c8 = (off % (BN * 2)) >> 4;       // original 8-elem chunk
      int rc8 = c8 ^ ((row >> 2) & 3);      // inverse swizzle
      bf16x8 vv = *(const bf16x8*)&Cs[row * BN + rc8 * 8];
      *(bf16x8*)&((__bf16*)outp)[(size_t)(m0 + row) * N + n0 + c8 * 8] = vv;
    }
  } else {
#pragma unroll
    for (int j = 0; j < JN; ++j) {
      int col = n0 + wn + j * 16 + lane16;
      float bv = bias ? bias[col] : 0.f;
#pragma unroll
      for (int i = 0; i < MI; ++i) {
#pragma unroll
        for (int r = 0; r < 4; ++r) {
          int row = m0 + wm + i * 16 + quad * 4 + r;
          float v = acc[i][j][r] + bv;
          if (RELU) v = fmaxf(v, 0.f);
          if (OUT_BF16)
            ((__bf16*)outp)[(size_t)row * N + col] = (__bf16)v;
          else
            ((float*)outp)[(size_t)row * N + col] = v;
        }
      }
    }
  }
}

// ---- ff1: 1D grid with XCD-chunked swizzle (1024 = 8 x 128, bijective) ----
// Chunk of 128 consecutive logicals = 8 full row-panels on ONE XCD:
// x1b read once per XCD (vs 16x round-robin), W1 L2-resident per XCD.
__global__ __launch_bounds__(256) void k_ff1(
    const __bf16* __restrict__ A, const __bf16* __restrict__ Wn,
    const float* __restrict__ bias, __bf16* __restrict__ outp) {
  int bid = blockIdx.x;
  int blk = (bid & 7) * 128 + (bid >> 3);
  int bx = blk & 15, by = blk >> 4;
  gemm_body<128, 128, 1, 1>(A, Wn, bias, outp, bx * 128, by * 128, FF_, C_, 0, C_);
}

// ---- merged khv GEMM (1024 blocks) + qh GEMM (128 blocks) ----
// XCD-chunked swizzle (1152 = 8 x 144, bijective).
__global__ __launch_bounds__(256) void k_gemm2(
    const __bf16* __restrict__ keyTb, const __bf16* __restrict__ kvwb,
    __bf16* __restrict__ khvbuf,
    const __bf16* __restrict__ qinb, const __bf16* __restrict__ qwb,
    const float* __restrict__ q_b, __bf16* __restrict__ qhb) {
  int bid = blockIdx.x;
  int blk = (bid & 7) * 144 + (bid >> 3);
  const __bf16 *A, *Wn; const float* bias; __bf16* outp; int n0, m0, N;
  if (blk < 1024) {
    A = keyTb; Wn = kvwb; bias = nullptr; outp = khvbuf;
    n0 = (blk & 3) * 128; m0 = (blk >> 2) * 128; N = 512;
  } else {
    int l = blk - 1024;
    A = qinb; Wn = qwb; bias = q_b; outp = qhb;
    n0 = (l & 1) * 128; m0 = (l >> 1) * 128; N = 256;
  }
  gemm_body<128, 128, 0, 1>(A, Wn, bias, outp, n0, m0, N, 256, 0, 256);
}

// ======== v3: 8-wave N-split 32x256 GEMM core, 72KB LDS -> 2 blocks/CU ======
template <int K>
__device__ __forceinline__ void gemm32x256_v3(
    const __bf16* __restrict__ A, const __bf16* __restrict__ Wn,
    const float* __restrict__ bias, int m0, char* smem, float (*buf)[257]) {
  constexpr int NT = K / 64;
  int t = threadIdx.x;
  int lane = t & 63, w = t >> 6;
  int lane16 = lane & 15, quad = lane >> 4;
  int wn = w * 32;
  int l3 = lane >> 3, lc = lane & 7;

  char* As0 = smem;              // 2 bufs x 4KB
  char* Bs0 = smem + 8192;       // 2 bufs x 32KB

  f32x4 acc[2][2];
#pragma unroll
  for (int i = 0; i < 2; ++i)
#pragma unroll
    for (int j = 0; j < 2; ++j) acc[i][j] = (f32x4){0.f, 0.f, 0.f, 0.f};

  auto STAGE = [&](int bi, int ts) {
    int k0 = ts * 64;
    if (w < 4) {                       // A: 4 x 1KB (32 rows)
      int row = w * 8 + l3;
      gload_lds16(A + (size_t)(m0 + row) * K + k0 + ((lc ^ l3) << 3),
                  As0 + bi * 4096 + w * 1024);
    }
#pragma unroll
    for (int i = 0; i < 4; ++i) {      // B: 32 x 1KB (256 rows), 4 per wave
      int j = w * 4 + i;
      int row = j * 8 + l3;
      gload_lds16(Wn + (size_t)row * K + k0 + ((lc ^ l3) << 3),
                  Bs0 + bi * 32768 + j * 1024);
    }
  };

  STAGE(0, 0);
  __syncthreads();
  int cur = 0;
  for (int ts = 0; ts < NT; ++ts) {
    if (ts + 1 < NT) STAGE(cur ^ 1, ts + 1);
    const char* Ab = As0 + cur * 4096;
    const char* Bb = Bs0 + cur * 32768;
#pragma unroll
    for (int kk = 0; kk < 64; kk += 32) {
      int qc = (kk >> 3) + quad;
      int ch = qc ^ (lane16 & 7);
      bf16x8 af[2], bfr[2];
#pragma unroll
      for (int i = 0; i < 2; ++i)
        af[i] = *(const bf16x8*)(Ab + (i * 16 + lane16) * 128 + ch * 16);
#pragma unroll
      for (int j = 0; j < 2; ++j)
        bfr[j] = *(const bf16x8*)(Bb + (wn + j * 16 + lane16) * 128 + ch * 16);
#pragma unroll
      for (int i = 0; i < 2; ++i)
#pragma unroll
        for (int j = 0; j < 2; ++j)
          acc[i][j] = __builtin_amdgcn_mfma_f32_16x16x32_bf16(af[i], bfr[j], acc[i][j], 0, 0, 0);
    }
    __syncthreads();
    cur ^= 1;
  }

  // acc + bias -> buf (aliases stage LDS; all reads fenced by loop barrier)
#pragma unroll
  for (int j = 0; j < 2; ++j) {
    int col = wn + j * 16 + lane16;
    float bv = bias[col];
#pragma unroll
    for (int i = 0; i < 2; ++i)
#pragma unroll
      for (int r = 0; r < 4; ++r)
        buf[i * 16 + quad * 4 + r][col] = acc[i][j][r] + bv;
  }
  __syncthreads();
}

// ---- fused o-proj + residual(qtok) + LN1 -> x1b (512 thr, v3 core) ----
__global__ __launch_bounds__(512) void k_oln(
    const __bf16* __restrict__ A /*aob*/, const __bf16* __restrict__ Wn /*owb*/,
    const float* __restrict__ obias, const __bf16* __restrict__ qtokb,
    const float* __restrict__ g, const float* __restrict__ bb,
    __bf16* __restrict__ x1b) {
  __shared__ __align__(16) char smem[73728];
  float (*buf)[257] = (float(*)[257])smem;
  int m0 = blockIdx.x * 32;
  gemm32x256_v3<C_>(A, Wn, obias, m0, smem, buf);

  int t = threadIdx.x;
  int lane = t & 63, w = t >> 6;
  float4 g4 = *(const float4*)(g + lane * 4);
  float4 b4 = *(const float4*)(bb + lane * 4);
#pragma unroll
  for (int rr = 0; rr < 4; ++rr) {
    int row = w * 4 + rr;
    size_t grow = (size_t)(m0 + row);
    bf16x4 q4 = *(const bf16x4*)&qtokb[grow * C_ + lane * 4];
    float x0 = buf[row][lane * 4 + 0] + (float)q4[0];
    float x1 = buf[row][lane * 4 + 1] + (float)q4[1];
    float x2 = buf[row][lane * 4 + 2] + (float)q4[2];
    float x3 = buf[row][lane * 4 + 3] + (float)q4[3];
    float s = x0 + x1 + x2 + x3;
#pragma unroll
    for (int off = 32; off >= 1; off >>= 1) s += __shfl_xor(s, off);
    float mean = s * (1.f / C_);
    float d0 = x0 - mean, d1 = x1 - mean, d2 = x2 - mean, d3 = x3 - mean;
    float v = d0 * d0 + d1 * d1 + d2 * d2 + d3 * d3;
#pragma unroll
    for (int off = 32; off >= 1; off >>= 1) v += __shfl_xor(v, off);
    float inv = 1.f / sqrtf(v * (1.f / C_) + EPS_);
    __bf16* obp = x1b + grow * C_ + lane * 4;
    obp[0] = (__bf16)(d0 * inv * g4.x + b4.x);
    obp[1] = (__bf16)(d1 * inv * g4.y + b4.y);
    obp[2] = (__bf16)(d2 * inv * g4.z + b4.z);
    obp[3] = (__bf16)(d3 * inv * g4.w + b4.w);
  }
}

// ---- fused ff2 + residual(x1b) + LN2 + transpose -> out (512 thr, v3) ----
__global__ __launch_bounds__(512) void k_ff2lnt(
    const __bf16* __restrict__ A /*ff1b*/, const __bf16* __restrict__ Wn /*l2b*/,
    const float* __restrict__ l2bias, const __bf16* __restrict__ x1b,
    const float* __restrict__ g, const float* __restrict__ bb,
    float* __restrict__ out) {
  __shared__ __align__(16) char smem[73728];
  float (*buf)[257] = (float(*)[257])smem;
  int m0 = blockIdx.x * 32;
  gemm32x256_v3<FF_>(A, Wn, l2bias, m0, smem, buf);

  int t = threadIdx.x;
  int lane = t & 63, w = t >> 6;
  float4 g4 = *(const float4*)(g + lane * 4);
  float4 b4 = *(const float4*)(bb + lane * 4);
#pragma unroll
  for (int rr = 0; rr < 4; ++rr) {
    int row = w * 4 + rr;
    size_t grow = (size_t)(m0 + row);
    bf16x4 v4 = *(const bf16x4*)&x1b[grow * C_ + lane * 4];
    float x0 = buf[row][lane * 4 + 0] + (float)v4[0];
    float x1 = buf[row][lane * 4 + 1] + (float)v4[1];
    float x2 = buf[row][lane * 4 + 2] + (float)v4[2];
    float x3 = buf[row][lane * 4 + 3] + (float)v4[3];
    float s = x0 + x1 + x2 + x3;
#pragma unroll
    for (int off = 32; off >= 1; off >>= 1) s += __shfl_xor(s, off);
    float mean = s * (1.f / C_);
    float d0 = x0 - mean, d1 = x1 - mean, d2 = x2 - mean, d3 = x3 - mean;
    float v = d0 * d0 + d1 * d1 + d2 * d2 + d3 * d3;
#pragma unroll
    for (int off = 32; off >= 1; off >>= 1) v += __shfl_xor(v, off);
    float inv = 1.f / sqrtf(v * (1.f / C_) + EPS_);
    buf[row][lane * 4 + 0] = d0 * inv * g4.x + b4.x;
    buf[row][lane * 4 + 1] = d1 * inv * g4.y + b4.y;
    buf[row][lane * 4 + 2] = d2 * inv * g4.z + b4.z;
    buf[row][lane * 4 + 3] = d3 * inv * g4.w + b4.w;
  }
  __syncthreads();
  int z = m0 >> 10, nq0 = m0 & (NQ_ - 1);
  int tx = t & 31, ty = t >> 5;   // ty in 0..15
#pragma unroll
  for (int ci = 0; ci < 16; ++ci) {
    int c = ci * 16 + ty;
    out[((size_t)z * C_ + c) * NQ_ + nq0 + tx] = buf[tx][c];
  }
}

// ---- fused attention (R4 form: K+V staged 520-pitch) ----
__global__ __launch_bounds__(256) void k_attnf(
    const __bf16* __restrict__ khv,
    const float* __restrict__ key_pos,
    const float* __restrict__ query_pos,
    const int* __restrict__ idx,
    const int* __restrict__ maskb,
    const __bf16* __restrict__ qhb,
    const float4* __restrict__ Pk,
    const float4* __restrict__ Pv,
    __bf16* __restrict__ aob) {
  __shared__ __bf16 kvs[S_][520];
  __shared__ float qrow[C_];
  __shared__ float sc[H_][S_];
  __shared__ float pw[H_][S_];
  __shared__ float4 gx4[S_];
  __shared__ float4 pgxs[H_];
  __shared__ float4 qpks[H_];
  __shared__ int srow[S_], smask[S_];
  int bq = blockIdx.x, b = bq >> 10, t = threadIdx.x;

  if (t < S_) {
    int k = idx[(size_t)bq * S_ + t];
    srow[t] = b * NK_ + k;
    smask[t] = maskb[(size_t)bq * S_ + t];
    const float* kpp = key_pos + ((size_t)b * NK_ + k) * 3;
    const float* qp  = query_pos + (size_t)bq * 6;
    gx4[t] = make_float4(kpp[0] - qp[0], kpp[1] - qp[1], kpp[2] - qp[2], 1.f);
  }
  float qv_t = (float)qhb[(size_t)bq * C_ + t];
  qrow[t] = qv_t;
  {
    float4 p = Pk[t];
    p.x *= qv_t; p.y *= qv_t; p.z *= qv_t; p.w *= qv_t;
#pragma unroll
    for (int off = 16; off >= 1; off >>= 1) {
      p.x += __shfl_xor(p.x, off);
      p.y += __shfl_xor(p.y, off);
      p.z += __shfl_xor(p.z, off);
      p.w += __shfl_xor(p.w, off);
    }
    if ((t & 31) == 0) {
      const float s = 0.17677669529663687f;
      qpks[t >> 5] = make_float4(p.x * s, p.y * s, p.z * s, p.w * s);
    }
  }
  __syncthreads();
  {
    int s = t >> 4, c0 = (t & 15) * 32;
    const __bf16* src = khv + (size_t)srow[s] * 512 + c0;
    *(bf16x8*)&kvs[s][c0]      = *(const bf16x8*)&src[0];
    *(bf16x8*)&kvs[s][c0 + 8]  = *(const bf16x8*)&src[8];
    *(bf16x8*)&kvs[s][c0 + 16] = *(const bf16x8*)&src[16];
    *(bf16x8*)&kvs[s][c0 + 24] = *(const bf16x8*)&src[24];
  }
  __syncthreads();
  if (t < H_ * S_) {
    int h = t >> 4, s = t & (S_ - 1);
    float d = 0.f;
#pragma unroll
    for (int c0 = 0; c0 < 32; c0 += 8) {
      bf16x8 xv = *(const bf16x8*)&kvs[s][h * 32 + c0];
#pragma unroll
      for (int j = 0; j < 8; ++j) d += qrow[h * 32 + c0 + j] * (float)xv[j];
    }
    d *= 0.17677669529663687f;
    float4 g = gx4[s];
    float4 pk = qpks[h];
    d += g.x * pk.x + g.y * pk.y + g.z * pk.z + pk.w;
    if (smask[s]) d = -1e30f;
    sc[h][s] = d;
  }
  __syncthreads();
  if (t < H_) {
    float mx = -3.4e38f;
#pragma unroll
    for (int s = 0; s < S_; ++s) mx = fmaxf(mx, sc[t][s]);
    float e[S_], sum = 0.f;
#pragma unroll
    for (int s = 0; s < S_; ++s) { e[s] = expf(sc[t][s] - mx); sum += e[s]; }
    float inv = 1.f / sum;
    float gxx = 0.f, gyy = 0.f, gzz = 0.f;
#pragma unroll
    for (int s = 0; s < S_; ++s) {
      float p = e[s] * inv;
      pw[t][s] = p;
      float4 g = gx4[s];
      gxx += p * g.x; gyy += p * g.y; gzz += p * g.z;
    }
    pgxs[t] = make_float4(gxx, gyy, gzz, 1.f);
  }
  __syncthreads();
  {
    int h = t >> 5;
    float a = 0.f;
#pragma unroll
    for (int s = 0; s < S_; ++s) a += pw[h][s] * (float)kvs[s][256 + t];
    float4 pv = Pv[t];
    float4 g = pgxs[h];
    a += g.x * pv.x + g.y * pv.y + g.z * pv.z + pv.w;
    aob[(size_t)bq * C_ + t] = (__bf16)a;
  }
}

extern "C" void kernel_launch(void* const* d_in, const int* in_sizes, int n_in,
                              void* d_out, int out_size, void* d_ws, size_t ws_size,
                              hipStream_t stream) {
  const float* query     = (const float*)d_in[0];
  const float* key       = (const float*)d_in[1];
  const float* query_pos = (const float*)d_in[2];
  const float* key_pos   = (const float*)d_in[3];
  const float* q_w = (const float*)d_in[4];  const float* q_b = (const float*)d_in[5];
  const float* k_w = (const float*)d_in[6];  const float* k_b = (const float*)d_in[7];
  const float* v_w = (const float*)d_in[8];  const float* v_b = (const float*)d_in[9];
  const float* o_w = (const float*)d_in[10]; const float* o_b = (const float*)d_in[11];
  const float* lin1_w = (const float*)d_in[12]; const float* lin1_b = (const float*)d_in[13];
  const float* lin2_w = (const float*)d_in[14]; const float* lin2_b = (const float*)d_in[15];
  const float* n1_g = (const float*)d_in[16]; const float* n1_b = (const float*)d_in[17];
  const float* n2_g = (const float*)d_in[18]; const float* n2_b = (const float*)d_in[19];
  const float* qpe_w = (const float*)d_in[20]; const float* qpe_b = (const float*)d_in[21];
  const float* kpe_w = (const float*)d_in[22]; const float* kpe_b = (const float*)d_in[23];
  float* out = (float*)d_out;

  const size_t BQc = (size_t)BQ_ * C_;
  float* w = (float*)d_ws;
  size_t o = 0;
  // ---- workspace carve ----
  __bf16* keyTb = (__bf16*)(w + o); o += (size_t)B_ * NK_ * C_ / 2;   // 16.8 MB
  __bf16* qtokb = (__bf16*)(w + o); o += BQc / 2;
  __bf16* khvbuf = (__bf16*)(w + o); o += (size_t)B_ * NK_ * 512 / 2; // 33.5 MB; ff1b overlay
  __bf16* qinb = (__bf16*)(w + o); o += BQc / 2;
  __bf16* qhb  = (__bf16*)(w + o); o += BQc / 2;
  __bf16* aob  = (__bf16*)(w + o); o += BQc / 2;
  __bf16* x1b  = (__bf16*)(w + o); o += BQc / 2;
  __bf16* qwb  = (__bf16*)(w + o); o += (size_t)C_ * C_ / 2;
  __bf16* kvwb = (__bf16*)(w + o); o += (size_t)C_ * C_;              // (512,256) = k_w ++ v_w
  __bf16* owb  = (__bf16*)(w + o); o += (size_t)C_ * C_ / 2;
  __bf16* l1b  = (__bf16*)(w + o); o += (size_t)C_ * FF_ / 2;
  __bf16* l2b  = (__bf16*)(w + o); o += (size_t)C_ * FF_ / 2;
  float4* Pk   = (float4*)(w + o); o += C_ * 4;
  float4* Pv   = (float4*)(w + o); o += C_ * 4;
  int* idxb  = (int*)(w + o); o += (size_t)BQ_ * S_;
  int* maskb = (int*)(w + o); o += (size_t)BQ_ * S_;
  __bf16* ff1b = khvbuf;    // khv dead after attnf

  // 1. all preprocessing in one launch (box query first — latency-bound)
  CvtArgs ca;
  ca.src[0] = q_w; ca.dst[0] = qwb;
  ca.src[1] = k_w; ca.dst[1] = kvwb;
  ca.src[2] = v_w; ca.dst[2] = kvwb + (size_t)C_ * C_;
  ca.src[3] = o_w; ca.dst[3] = owb;
  ca.src[4] = lin1_w; ca.dst[4] = l1b;
  ca.src[5] = lin2_w; ca.dst[5] = l2b;
  k_prep<<<NPREP, 256, 0, stream>>>(query, key, query_pos, key_pos,
                                    qpe_w, qpe_b, k_w, k_b, v_w, v_b,
                                    kpe_w, kpe_b, ca,
                                    keyTb, qtokb, qinb, Pk, Pv, idxb, maskb);
  // 2. khv = key_feat @ [k_w|v_w]^T  +  qh = qin @ q_w.T + q_b (XCD-swizzled)
  k_gemm2<<<1024 + 128, 256, 0, stream>>>(keyTb, kvwb, khvbuf, qinb, qwb, q_b, qhb);
  // 3. fused attention
  k_attnf<<<BQ_, 256, 0, stream>>>(khvbuf, key_pos, query_pos, idxb, maskb,
                                   qhb, Pk, Pv, aob);
  // 4. fused o-proj + residual + LN1 -> x1b (512 thr, v3: 2 blocks/CU)
  k_oln<<<BQ_ / 32, 512, 0, stream>>>(aob, owb, o_b, qtokb, n1_g, n1_b, x1b);
  // 5. ff1(bf16) = relu(x1b @ lin1.T + b)   [overlays khvbuf; XCD-swizzled]
  k_ff1<<<1024, 256, 0, stream>>>(x1b, l1b, lin1_b, ff1b);
  // 6. fused ff2 + residual + LN2 + transpose -> out (512 thr, v3: 2 blocks/CU)
  k_ff2lnt<<<BQ_ / 32, 512, 0, stream>>>(ff1b, l2b, lin2_b, x1b, n2_g, n2_b, out);
}

// Round 11
// 243.841 us; speedup vs baseline: 1.0141x; 1.0141x over previous
//
#include <hip/hip_runtime.h>
#include <cstdint>

#define B_   8
#define C_   256
#define NQ_  1024
#define NK_  4096
#define S_   16
#define H_   8
#define FF_  2048
#define DH_  32
#define BQ_  (B_*NQ_)
#define EPS_ 1e-5f

typedef __bf16 bf16x8 __attribute__((ext_vector_type(8)));
typedef __bf16 bf16x4 __attribute__((ext_vector_type(4)));
typedef float  f32x4  __attribute__((ext_vector_type(4)));

struct CvtArgs {
  const float* src[6];
  __bf16* dst[6];
};

// async global->LDS DMA, 16B per lane. LDS dest is wave-uniform base + lane*16.
__device__ __forceinline__ void gload_lds16(const void* g, void* l) {
  __builtin_amdgcn_global_load_lds(
      (const __attribute__((address_space(1))) void*)g,
      (__attribute__((address_space(3))) void*)l, 16, 0, 0);
}

// ================= k_prep: one launch for all preprocessing =================
#define SEGA 2048
#define SEGB 10240
#define SEGC 12288
#define SEGD 13568
#define NPREP 13584

__global__ __launch_bounds__(256) void k_prep(
    const float* __restrict__ query, const float* __restrict__ key,
    const float* __restrict__ query_pos, const float* __restrict__ key_pos,
    const float* __restrict__ qpe_w, const float* __restrict__ qpe_b,
    const float* __restrict__ k_w, const float* __restrict__ k_b,
    const float* __restrict__ v_w, const float* __restrict__ v_b,
    const float* __restrict__ kpe_w, const float* __restrict__ kpe_b,
    CvtArgs ca,
    __bf16* __restrict__ keyTb, __bf16* __restrict__ qtokb,
    __bf16* __restrict__ qinb,
    float4* __restrict__ Pk, float4* __restrict__ Pv,
    int* __restrict__ idxo, int* __restrict__ masko) {
  __shared__ __align__(16) float smem[1248];
  int blk = blockIdx.x, t = threadIdx.x;
  int tx = t & 31, ty = t >> 5;

  if (blk < SEGA) {
    // ---- box query: batched 4-chunk scan ----
    int lane = t & 63;
    int q = blk * 4 + (t >> 6);
    int b = q >> 10;
    const float* kpb = key_pos + (size_t)b * NK_ * 3;
    const float* qp = query_pos + (size_t)q * 6;
    float cx = qp[0], cy = qp[1], cz = qp[2];
    float hx = 0.5f * qp[3], hy = 0.5f * qp[4], hz = 0.5f * qp[5];
    int* iq = idxo + (size_t)q * S_;
    int found = 0;
    for (int ch = 0; ch < NK_ / 64; ch += 4) {
      float dx[4], dy[4], dz[4];
#pragma unroll
      for (int u = 0; u < 4; ++u) {
        int k = (ch + u) * 64 + lane;
        dx[u] = fabsf(kpb[k * 3 + 0] - cx);
        dy[u] = fabsf(kpb[k * 3 + 1] - cy);
        dz[u] = fabsf(kpb[k * 3 + 2] - cz);
      }
#pragma unroll
      for (int u = 0; u < 4; ++u) {
        bool inside = (dx[u] <= hx) && (dy[u] <= hy) && (dz[u] <= hz);
        unsigned long long bal = __ballot(inside);
        if (inside) {
          int slot = found + __popcll(bal & ((1ull << lane) - 1ull));
          if (slot < S_) iq[slot] = (ch + u) * 64 + lane;
        }
        found += __popcll(bal);
      }
      if (found >= S_) break;
    }
    if (found > S_) found = S_;
    if (lane < S_) {
      int m = (lane < found) ? 0 : 1;
      if (lane >= found) iq[lane] = 0;
      if (lane == 0) m = 0;
      masko[(size_t)q * S_ + lane] = m;
    }
  } else if (blk < SEGB) {
    // ---- key transpose ----
    int local = blk - SEGA;
    float (*tt)[33] = (float(*)[33])smem;
    int x = local & 127, y = (local >> 7) & 7, z = local >> 10;
    int j0 = x * 32, i0 = y * 32;
    const float* inz = key + (size_t)z * C_ * NK_;
    __bf16* outz = keyTb + (size_t)z * NK_ * C_;
#pragma unroll
    for (int r = 0; r < 32; r += 8)
      tt[ty + r][tx] = inz[(size_t)(i0 + ty + r) * NK_ + (j0 + tx)];
    __syncthreads();
#pragma unroll
    for (int r = 0; r < 32; r += 8)
      outz[(size_t)(j0 + ty + r) * C_ + (i0 + tx)] = (__bf16)tt[tx][ty + r];
  } else if (blk < SEGC) {
    // ---- query transpose + qpe (both outputs bf16) ----
    int local = blk - SEGB;
    float (*tt)[33] = (float(*)[33])smem;
    float (*sqp)[6] = (float(*)[6])(smem + 1056);
    int x = local & 31, y = (local >> 5) & 7, z = local >> 8;
    int nq0 = x * 32, c0 = y * 32;
    const float* inz = query + (size_t)z * C_ * NQ_;
#pragma unroll
    for (int r = 0; r < 32; r += 8)
      tt[ty + r][tx] = inz[(size_t)(c0 + ty + r) * NQ_ + (nq0 + tx)];
    if (t < 192)
      sqp[t / 6][t % 6] = query_pos[((size_t)z * NQ_ + nq0 + t / 6) * 6 + (t % 6)];
    int c = c0 + tx;
    float w0 = qpe_w[c * 6 + 0], w1 = qpe_w[c * 6 + 1], w2 = qpe_w[c * 6 + 2];
    float w3 = qpe_w[c * 6 + 3], w4 = qpe_w[c * 6 + 4], w5 = qpe_w[c * 6 + 5];
    float wb = qpe_b[c];
    __syncthreads();
#pragma unroll
    for (int r = 0; r < 32; r += 8) {
      int nql = ty + r;
      size_t row = (size_t)z * NQ_ + nq0 + nql;
      float v = tt[tx][nql];
      float pe = wb + sqp[nql][0] * w0 + sqp[nql][1] * w1 + sqp[nql][2] * w2 +
                 sqp[nql][3] * w3 + sqp[nql][4] * w4 + sqp[nql][5] * w5;
      qtokb[row * C_ + c] = (__bf16)v;
      qinb[row * C_ + c] = (__bf16)(v + pe);
    }
  } else if (blk < SEGD) {
    // ---- weight casts ----
    int local = blk - SEGC;
    int idx, base;
    if (local < 64)       { idx = 0; base = local; }
    else if (local < 128) { idx = 1; base = local - 64; }
    else if (local < 192) { idx = 2; base = local - 128; }
    else if (local < 256) { idx = 3; base = local - 192; }
    else if (local < 768) { idx = 4; base = local - 256; }
    else                  { idx = 5; base = local - 768; }
    size_t off = (size_t)base * 1024 + t * 4;
    float4 v = *(const float4*)(ca.src[idx] + off);
    __bf16* o = ca.dst[idx] + off;
    o[0] = (__bf16)v.x; o[1] = (__bf16)v.y; o[2] = (__bf16)v.z; o[3] = (__bf16)v.w;
  } else {
    // ---- Pk / Pv fold ----
    int local = blk - SEGD;
    int bx = local & 7, bv = local >> 3;
    const float* w  = bv ? v_w : k_w;
    const float* wb = bv ? v_b : k_b;
    float4* P = bv ? Pv : Pk;
    float4 (*red)[8] = (float4(*)[8])smem;
    int nl = t >> 3, ks = (t & 7) * 32;
    int n = bx * 32 + nl;
    const float* wr = w + (size_t)n * C_;
    float p0 = 0.f, p1 = 0.f, p2 = 0.f, pb = 0.f;
#pragma unroll
    for (int k = ks; k < ks + 32; ++k) {
      float wv = wr[k];
      p0 += kpe_w[k * 3 + 0] * wv;
      p1 += kpe_w[k * 3 + 1] * wv;
      p2 += kpe_w[k * 3 + 2] * wv;
      pb += kpe_b[k] * wv;
    }
    red[nl][t & 7] = make_float4(p0, p1, p2, pb);
    __syncthreads();
    if (t < 32) {
      float4 s = red[t][0];
#pragma unroll
      for (int j = 1; j < 8; ++j) {
        float4 r = red[t][j];
        s.x += r.x; s.y += r.y; s.z += r.z; s.w += r.w;
      }
      s.w += wb[bx * 32 + t];
      P[bx * 32 + t] = s;
    }
  }
}

// ============== core MFMA tile (4-wave, 256-thread kernels) ========
// global_load_lds(16B) into LINEAR [R][64] LDS, source-side chunk XOR-swizzle
// (chunk ^= row&7) mirrored on the ds_read side (2-way = free).
template <int BM, int BN>
__device__ __forceinline__ void gemm_tile(
    const __bf16* __restrict__ A, const __bf16* __restrict__ Wn,
    int m0, int n0, int K, int kbeg, int kend,
    __bf16 (*As)[64], __bf16 (*Bs)[64],
    f32x4 (&acc)[BM / 32][BN / 32]) {
  constexpr int MI = BM / 32, JN = BN / 32;
  constexpr int AI = BM / 32, BI = BN / 32;
  int t = threadIdx.x;
  int lane = t & 63, w = t >> 6;
  int lane16 = lane & 15, quad = lane >> 4;
  int wm = (w & 1) * (BM / 2), wn = (w >> 1) * (BN / 2);
  int l3 = lane >> 3;
  int lc = lane & 7;

  for (int k0 = kbeg; k0 < kend; k0 += 64) {
#pragma unroll
    for (int i = 0; i < AI; ++i) {
      int j = i * 4 + w;
      int row = j * 8 + l3;
      const __bf16* src = A + (size_t)(m0 + row) * K + k0 + ((lc ^ l3) << 3);
      gload_lds16(src, (char*)&As[0][0] + j * 1024);
    }
#pragma unroll
    for (int i = 0; i < BI; ++i) {
      int j = i * 4 + w;
      int row = j * 8 + l3;
      const __bf16* src = Wn + (size_t)(n0 + row) * K + k0 + ((lc ^ l3) << 3);
      gload_lds16(src, (char*)&Bs[0][0] + j * 1024);
    }
    __syncthreads();
#pragma unroll
    for (int kk = 0; kk < 64; kk += 32) {
      bf16x8 af[MI], bfr[JN];
      int qc = (kk >> 3) + quad;
#pragma unroll
      for (int i = 0; i < MI; ++i) {
        int row = wm + i * 16 + lane16;
        int ch = qc ^ (lane16 & 7);
        af[i] = *(const bf16x8*)((const char*)&As[row][0] + ch * 16);
      }
#pragma unroll
      for (int j = 0; j < JN; ++j) {
        int row = wn + j * 16 + lane16;
        int ch = qc ^ (lane16 & 7);
        bfr[j] = *(const bf16x8*)((const char*)&Bs[row][0] + ch * 16);
      }
#pragma unroll
      for (int i = 0; i < MI; ++i)
#pragma unroll
        for (int j = 0; j < JN; ++j)
          acc[i][j] = __builtin_amdgcn_mfma_f32_16x16x32_bf16(af[i], bfr[j], acc[i][j], 0, 0, 0);
    }
    __syncthreads();
  }
}

// ============== generic GEMM with LDS-staged coalesced epilogue ==============
template <int BM, int BN, int RELU, int OUT_BF16>
__device__ __forceinline__ void gemm_body(
    const __bf16* __restrict__ A, const __bf16* __restrict__ Wn,
    const float* __restrict__ bias, void* __restrict__ outp,
    int n0, int m0, int N, int K, int kbeg, int kend) {
  constexpr int MI = BM / 32, JN = BN / 32;
  __shared__ __align__(16) char smem[(BM + BN) * 128];
  __bf16 (*As)[64] = (__bf16(*)[64])smem;
  __bf16 (*Bs)[64] = (__bf16(*)[64])(smem + (size_t)BM * 128);
  int t = threadIdx.x;
  int lane = t & 63, w = t >> 6;
  int lane16 = lane & 15, quad = lane >> 4;
  int wm = (w & 1) * (BM / 2), wn = (w >> 1) * (BN / 2);

  f32x4 acc[MI][JN];
#pragma unroll
  for (int i = 0; i < MI; ++i)
#pragma unroll
    for (int j = 0; j < JN; ++j) acc[i][j] = (f32x4){0.f, 0.f, 0.f, 0.f};

  gemm_tile<BM, BN>(A, Wn, m0, n0, K, kbeg, kend, As, Bs, acc);

  if constexpr (OUT_BF16 && (BM * BN * 2 <= (BM + BN) * 128)) {
    __bf16* Cs = (__bf16*)smem;   // BM*BN bf16, aliases dead As/Bs
#pragma unroll
    for (int j = 0; j < JN; ++j) {
      int col = wn + j * 16 + lane16;
      float bv = bias ? bias[n0 + col] : 0.f;
#pragma unroll
      for (int i = 0; i < MI; ++i)
#pragma unroll
        for (int r = 0; r < 4; ++r) {
          int row = wm + i * 16 + quad * 4 + r;
          float v = acc[i][j][r] + bv;
          if (RELU) v = fmaxf(v, 0.f);
          int sw = ((col >> 3) ^ ((row >> 2) & 3)) * 8 + (col & 7);
          Cs[row * BN + sw] = (__bf16)v;
        }
    }
    __syncthreads();
    constexpr int PASSES = BM * BN * 2 / (256 * 16);
#pragma unroll
    for (int p = 0; p < PASSES; ++p) {
      int off = p * 4096 + t * 16;          // byte offset within C tile
      int row = off / (BN * 2);
      int c8 = (off % (BN * 2)) >> 4;       // original 8-elem chunk
      int rc8 = c8 ^ ((row >> 2) & 3);      // inverse swizzle
      bf16x8 vv = *(const bf16x8*)&Cs[row * BN + rc8 * 8];
      *(bf16x8*)&((__bf16*)outp)[(size_t)(m0 + row) * N + n0 + c8 * 8] = vv;
    }
  } else {
#pragma unroll
    for (int j = 0; j < JN; ++j) {
      int col = n0 + wn + j * 16 + lane16;
      float bv = bias ? bias[col] : 0.f;
#pragma unroll
      for (int i = 0; i < MI; ++i) {
#pragma unroll
        for (int r = 0; r < 4; ++r) {
          int row = m0 + wm + i * 16 + quad * 4 + r;
          float v = acc[i][j][r] + bv;
          if (RELU) v = fmaxf(v, 0.f);
          if (OUT_BF16)
            ((__bf16*)outp)[(size_t)row * N + col] = (__bf16)v;
          else
            ((float*)outp)[(size_t)row * N + col] = v;
        }
      }
    }
  }
}

template <int BM, int BN, int RELU, int OUT_BF16>
__global__ __launch_bounds__(256) void k_gemm(
    const __bf16* __restrict__ A, const __bf16* __restrict__ Wn,
    const float* __restrict__ bias, void* __restrict__ outp, int N, int K) {
  gemm_body<BM, BN, RELU, OUT_BF16>(A, Wn, bias, outp,
                                    blockIdx.x * BN, blockIdx.y * BM, N, K, 0, K);
}

// ---- merged khv GEMM (1024 blocks) + qh GEMM (128 blocks) ----
// XCD-chunked swizzle (1152 = 8 x 144, bijective).
__global__ __launch_bounds__(256) void k_gemm2(
    const __bf16* __restrict__ keyTb, const __bf16* __restrict__ kvwb,
    __bf16* __restrict__ khvbuf,
    const __bf16* __restrict__ qinb, const __bf16* __restrict__ qwb,
    const float* __restrict__ q_b, __bf16* __restrict__ qhb) {
  int bid = blockIdx.x;
  int blk = (bid & 7) * 144 + (bid >> 3);
  const __bf16 *A, *Wn; const float* bias; __bf16* outp; int n0, m0, N;
  if (blk < 1024) {
    A = keyTb; Wn = kvwb; bias = nullptr; outp = khvbuf;
    n0 = (blk & 3) * 128; m0 = (blk >> 2) * 128; N = 512;
  } else {
    int l = blk - 1024;
    A = qinb; Wn = qwb; bias = q_b; outp = qhb;
    n0 = (l & 1) * 128; m0 = (l >> 1) * 128; N = 256;
  }
  gemm_body<128, 128, 0, 1>(A, Wn, bias, outp, n0, m0, N, 256, 0, 256);
}

// ======== v3: 8-wave N-split 32x256 GEMM core, 72KB LDS -> 2 blocks/CU ======
template <int K>
__device__ __forceinline__ void gemm32x256_v3(
    const __bf16* __restrict__ A, const __bf16* __restrict__ Wn,
    const float* __restrict__ bias, int m0, char* smem, float (*buf)[257]) {
  constexpr int NT = K / 64;
  int t = threadIdx.x;
  int lane = t & 63, w = t >> 6;
  int lane16 = lane & 15, quad = lane >> 4;
  int wn = w * 32;
  int l3 = lane >> 3, lc = lane & 7;

  char* As0 = smem;              // 2 bufs x 4KB
  char* Bs0 = smem + 8192;       // 2 bufs x 32KB

  f32x4 acc[2][2];
#pragma unroll
  for (int i = 0; i < 2; ++i)
#pragma unroll
    for (int j = 0; j < 2; ++j) acc[i][j] = (f32x4){0.f, 0.f, 0.f, 0.f};

  auto STAGE = [&](int bi, int ts) {
    int k0 = ts * 64;
    if (w < 4) {                       // A: 4 x 1KB (32 rows)
      int row = w * 8 + l3;
      gload_lds16(A + (size_t)(m0 + row) * K + k0 + ((lc ^ l3) << 3),
                  As0 + bi * 4096 + w * 1024);
    }
#pragma unroll
    for (int i = 0; i < 4; ++i) {      // B: 32 x 1KB (256 rows), 4 per wave
      int j = w * 4 + i;
      int row = j * 8 + l3;
      gload_lds16(Wn + (size_t)row * K + k0 + ((lc ^ l3) << 3),
                  Bs0 + bi * 32768 + j * 1024);
    }
  };

  STAGE(0, 0);
  __syncthreads();
  int cur = 0;
  for (int ts = 0; ts < NT; ++ts) {
    if (ts + 1 < NT) STAGE(cur ^ 1, ts + 1);
    const char* Ab = As0 + cur * 4096;
    const char* Bb = Bs0 + cur * 32768;
#pragma unroll
    for (int kk = 0; kk < 64; kk += 32) {
      int qc = (kk >> 3) + quad;
      int ch = qc ^ (lane16 & 7);
      bf16x8 af[2], bfr[2];
#pragma unroll
      for (int i = 0; i < 2; ++i)
        af[i] = *(const bf16x8*)(Ab + (i * 16 + lane16) * 128 + ch * 16);
#pragma unroll
      for (int j = 0; j < 2; ++j)
        bfr[j] = *(const bf16x8*)(Bb + (wn + j * 16 + lane16) * 128 + ch * 16);
#pragma unroll
      for (int i = 0; i < 2; ++i)
#pragma unroll
        for (int j = 0; j < 2; ++j)
          acc[i][j] = __builtin_amdgcn_mfma_f32_16x16x32_bf16(af[i], bfr[j], acc[i][j], 0, 0, 0);
    }
    __syncthreads();
    cur ^= 1;
  }

  // acc + bias -> buf (aliases stage LDS; all reads fenced by loop barrier)
#pragma unroll
  for (int j = 0; j < 2; ++j) {
    int col = wn + j * 16 + lane16;
    float bv = bias[col];
#pragma unroll
    for (int i = 0; i < 2; ++i)
#pragma unroll
      for (int r = 0; r < 4; ++r)
        buf[i * 16 + quad * 4 + r][col] = acc[i][j][r] + bv;
  }
  __syncthreads();
}

// ---- fused o-proj + residual(qtok) + LN1 -> x1b (512 thr, v3 core) ----
__global__ __launch_bounds__(512) void k_oln(
    const __bf16* __restrict__ A /*aob*/, const __bf16* __restrict__ Wn /*owb*/,
    const float* __restrict__ obias, const __bf16* __restrict__ qtokb,
    const float* __restrict__ g, const float* __restrict__ bb,
    __bf16* __restrict__ x1b) {
  __shared__ __align__(16) char smem[73728];
  float (*buf)[257] = (float(*)[257])smem;
  int m0 = blockIdx.x * 32;
  gemm32x256_v3<C_>(A, Wn, obias, m0, smem, buf);

  int t = threadIdx.x;
  int lane = t & 63, w = t >> 6;
  float4 g4 = *(const float4*)(g + lane * 4);
  float4 b4 = *(const float4*)(bb + lane * 4);
#pragma unroll
  for (int rr = 0; rr < 4; ++rr) {
    int row = w * 4 + rr;
    size_t grow = (size_t)(m0 + row);
    bf16x4 q4 = *(const bf16x4*)&qtokb[grow * C_ + lane * 4];
    float x0 = buf[row][lane * 4 + 0] + (float)q4[0];
    float x1 = buf[row][lane * 4 + 1] + (float)q4[1];
    float x2 = buf[row][lane * 4 + 2] + (float)q4[2];
    float x3 = buf[row][lane * 4 + 3] + (float)q4[3];
    float s = x0 + x1 + x2 + x3;
#pragma unroll
    for (int off = 32; off >= 1; off >>= 1) s += __shfl_xor(s, off);
    float mean = s * (1.f / C_);
    float d0 = x0 - mean, d1 = x1 - mean, d2 = x2 - mean, d3 = x3 - mean;
    float v = d0 * d0 + d1 * d1 + d2 * d2 + d3 * d3;
#pragma unroll
    for (int off = 32; off >= 1; off >>= 1) v += __shfl_xor(v, off);
    float inv = 1.f / sqrtf(v * (1.f / C_) + EPS_);
    __bf16* obp = x1b + grow * C_ + lane * 4;
    obp[0] = (__bf16)(d0 * inv * g4.x + b4.x);
    obp[1] = (__bf16)(d1 * inv * g4.y + b4.y);
    obp[2] = (__bf16)(d2 * inv * g4.z + b4.z);
    obp[3] = (__bf16)(d3 * inv * g4.w + b4.w);
  }
}

// ---- fused ff2 + residual(x1b) + LN2 + transpose -> out (512 thr, v3) ----
__global__ __launch_bounds__(512) void k_ff2lnt(
    const __bf16* __restrict__ A /*ff1b*/, const __bf16* __restrict__ Wn /*l2b*/,
    const float* __restrict__ l2bias, const __bf16* __restrict__ x1b,
    const float* __restrict__ g, const float* __restrict__ bb,
    float* __restrict__ out) {
  __shared__ __align__(16) char smem[73728];
  float (*buf)[257] = (float(*)[257])smem;
  int m0 = blockIdx.x * 32;
  gemm32x256_v3<FF_>(A, Wn, l2bias, m0, smem, buf);

  int t = threadIdx.x;
  int lane = t & 63, w = t >> 6;
  float4 g4 = *(const float4*)(g + lane * 4);
  float4 b4 = *(const float4*)(bb + lane * 4);
#pragma unroll
  for (int rr = 0; rr < 4; ++rr) {
    int row = w * 4 + rr;
    size_t grow = (size_t)(m0 + row);
    bf16x4 v4 = *(const bf16x4*)&x1b[grow * C_ + lane * 4];
    float x0 = buf[row][lane * 4 + 0] + (float)v4[0];
    float x1 = buf[row][lane * 4 + 1] + (float)v4[1];
    float x2 = buf[row][lane * 4 + 2] + (float)v4[2];
    float x3 = buf[row][lane * 4 + 3] + (float)v4[3];
    float s = x0 + x1 + x2 + x3;
#pragma unroll
    for (int off = 32; off >= 1; off >>= 1) s += __shfl_xor(s, off);
    float mean = s * (1.f / C_);
    float d0 = x0 - mean, d1 = x1 - mean, d2 = x2 - mean, d3 = x3 - mean;
    float v = d0 * d0 + d1 * d1 + d2 * d2 + d3 * d3;
#pragma unroll
    for (int off = 32; off >= 1; off >>= 1) v += __shfl_xor(v, off);
    float inv = 1.f / sqrtf(v * (1.f / C_) + EPS_);
    buf[row][lane * 4 + 0] = d0 * inv * g4.x + b4.x;
    buf[row][lane * 4 + 1] = d1 * inv * g4.y + b4.y;
    buf[row][lane * 4 + 2] = d2 * inv * g4.z + b4.z;
    buf[row][lane * 4 + 3] = d3 * inv * g4.w + b4.w;
  }
  __syncthreads();
  int z = m0 >> 10, nq0 = m0 & (NQ_ - 1);
  int tx = t & 31, ty = t >> 5;   // ty in 0..15
#pragma unroll
  for (int ci = 0; ci < 16; ++ci) {
    int c = ci * 16 + ty;
    out[((size_t)z * C_ + c) * NQ_ + nq0 + tx] = buf[tx][c];
  }
}

// ---- fused attention: wave-parallel softmax (m166 pattern) ----
__global__ __launch_bounds__(256) void k_attnf(
    const __bf16* __restrict__ khv,
    const float* __restrict__ key_pos,
    const float* __restrict__ query_pos,
    const int* __restrict__ idx,
    const int* __restrict__ maskb,
    const __bf16* __restrict__ qhb,
    const float4* __restrict__ Pk,
    const float4* __restrict__ Pv,
    __bf16* __restrict__ aob) {
  __shared__ __bf16 kvs[S_][520];
  __shared__ float qrow[C_];
  __shared__ float sc[H_][S_];
  __shared__ float pw[H_][S_];
  __shared__ float4 gx4[S_];
  __shared__ float4 pgxs[H_];
  __shared__ float4 qpks[H_];
  __shared__ int srow[S_], smask[S_];
  int bq = blockIdx.x, b = bq >> 10, t = threadIdx.x;

  if (t < S_) {
    int k = idx[(size_t)bq * S_ + t];
    srow[t] = b * NK_ + k;
    smask[t] = maskb[(size_t)bq * S_ + t];
    const float* kpp = key_pos + ((size_t)b * NK_ + k) * 3;
    const float* qp  = query_pos + (size_t)bq * 6;
    gx4[t] = make_float4(kpp[0] - qp[0], kpp[1] - qp[1], kpp[2] - qp[2], 1.f);
  }
  float qv_t = (float)qhb[(size_t)bq * C_ + t];
  qrow[t] = qv_t;
  {
    float4 p = Pk[t];
    p.x *= qv_t; p.y *= qv_t; p.z *= qv_t; p.w *= qv_t;
#pragma unroll
    for (int off = 16; off >= 1; off >>= 1) {
      p.x += __shfl_xor(p.x, off);
      p.y += __shfl_xor(p.y, off);
      p.z += __shfl_xor(p.z, off);
      p.w += __shfl_xor(p.w, off);
    }
    if ((t & 31) == 0) {
      const float s = 0.17677669529663687f;
      qpks[t >> 5] = make_float4(p.x * s, p.y * s, p.z * s, p.w * s);
    }
  }
  __syncthreads();
  {
    int s = t >> 4, c0 = (t & 15) * 32;
    const __bf16* src = khv + (size_t)srow[s] * 512 + c0;
    *(bf16x8*)&kvs[s][c0]      = *(const bf16x8*)&src[0];
    *(bf16x8*)&kvs[s][c0 + 8]  = *(const bf16x8*)&src[8];
    *(bf16x8*)&kvs[s][c0 + 16] = *(const bf16x8*)&src[16];
    *(bf16x8*)&kvs[s][c0 + 24] = *(const bf16x8*)&src[24];
  }
  __syncthreads();
  if (t < H_ * S_) {
    int h = t >> 4, s = t & (S_ - 1);
    float d = 0.f;
#pragma unroll
    for (int c0 = 0; c0 < 32; c0 += 8) {
      bf16x8 xv = *(const bf16x8*)&kvs[s][h * 32 + c0];
#pragma unroll
      for (int j = 0; j < 8; ++j) d += qrow[h * 32 + c0 + j] * (float)xv[j];
    }
    d *= 0.17677669529663687f;
    float4 g = gx4[s];
    float4 pk = qpks[h];
    d += g.x * pk.x + g.y * pk.y + g.z * pk.z + pk.w;
    if (smask[s]) d = -1e30f;
    sc[h][s] = d;
  }
  __syncthreads();
  {
    // wave-parallel softmax: head h = half-wave (32 lanes), lane i holds
    // score s=i&15 (duplicated in both 16-clusters); shfl_xor reduces over 16.
    int h = t >> 5, i = t & 31;
    float sci = sc[h][i & 15];
    float mx = sci;
#pragma unroll
    for (int off = 8; off >= 1; off >>= 1) mx = fmaxf(mx, __shfl_xor(mx, off));
    float e = expf(sci - mx);
    float sum = e;
#pragma unroll
    for (int off = 8; off >= 1; off >>= 1) sum += __shfl_xor(sum, off);
    float p = e * (1.f / sum);
    if (i < 16) pw[h][i] = p;
    float4 g = gx4[i & 15];
    float gxx = p * g.x, gyy = p * g.y, gzz = p * g.z;
#pragma unroll
    for (int off = 8; off >= 1; off >>= 1) {
      gxx += __shfl_xor(gxx, off);
      gyy += __shfl_xor(gyy, off);
      gzz += __shfl_xor(gzz, off);
    }
    if (i == 0) pgxs[h] = make_float4(gxx, gyy, gzz, 1.f);
  }
  __syncthreads();
  {
    int h = t >> 5;
    float a = 0.f;
#pragma unroll
    for (int s = 0; s < S_; ++s) a += pw[h][s] * (float)kvs[s][256 + t];
    float4 pv = Pv[t];
    float4 g = pgxs[h];
    a += g.x * pv.x + g.y * pv.y + g.z * pv.z + pv.w;
    aob[(size_t)bq * C_ + t] = (__bf16)a;
  }
}

extern "C" void kernel_launch(void* const* d_in, const int* in_sizes, int n_in,
                              void* d_out, int out_size, void* d_ws, size_t ws_size,
                              hipStream_t stream) {
  const float* query     = (const float*)d_in[0];
  const float* key       = (const float*)d_in[1];
  const float* query_pos = (const float*)d_in[2];
  const float* key_pos   = (const float*)d_in[3];
  const float* q_w = (const float*)d_in[4];  const float* q_b = (const float*)d_in[5];
  const float* k_w = (const float*)d_in[6];  const float* k_b = (const float*)d_in[7];
  const float* v_w = (const float*)d_in[8];  const float* v_b = (const float*)d_in[9];
  const float* o_w = (const float*)d_in[10]; const float* o_b = (const float*)d_in[11];
  const float* lin1_w = (const float*)d_in[12]; const float* lin1_b = (const float*)d_in[13];
  const float* lin2_w = (const float*)d_in[14]; const float* lin2_b = (const float*)d_in[15];
  const float* n1_g = (const float*)d_in[16]; const float* n1_b = (const float*)d_in[17];
  const float* n2_g = (const float*)d_in[18]; const float* n2_b = (const float*)d_in[19];
  const float* qpe_w = (const float*)d_in[20]; const float* qpe_b = (const float*)d_in[21];
  const float* kpe_w = (const float*)d_in[22]; const float* kpe_b = (const float*)d_in[23];
  float* out = (float*)d_out;

  const size_t BQc = (size_t)BQ_ * C_;
  float* w = (float*)d_ws;
  size_t o = 0;
  // ---- workspace carve ----
  __bf16* keyTb = (__bf16*)(w + o); o += (size_t)B_ * NK_ * C_ / 2;   // 16.8 MB
  __bf16* qtokb = (__bf16*)(w + o); o += BQc / 2;
  __bf16* khvbuf = (__bf16*)(w + o); o += (size_t)B_ * NK_ * 512 / 2; // 33.5 MB; ff1b overlay
  __bf16* qinb = (__bf16*)(w + o); o += BQc / 2;
  __bf16* qhb  = (__bf16*)(w + o); o += BQc / 2;
  __bf16* aob  = (__bf16*)(w + o); o += BQc / 2;
  __bf16* x1b  = (__bf16*)(w + o); o += BQc / 2;
  __bf16* qwb  = (__bf16*)(w + o); o += (size_t)C_ * C_ / 2;
  __bf16* kvwb = (__bf16*)(w + o); o += (size_t)C_ * C_;              // (512,256) = k_w ++ v_w
  __bf16* owb  = (__bf16*)(w + o); o += (size_t)C_ * C_ / 2;
  __bf16* l1b  = (__bf16*)(w + o); o += (size_t)C_ * FF_ / 2;
  __bf16* l2b  = (__bf16*)(w + o); o += (size_t)C_ * FF_ / 2;
  float4* Pk   = (float4*)(w + o); o += C_ * 4;
  float4* Pv   = (float4*)(w + o); o += C_ * 4;
  int* idxb  = (int*)(w + o); o += (size_t)BQ_ * S_;
  int* maskb = (int*)(w + o); o += (size_t)BQ_ * S_;
  __bf16* ff1b = khvbuf;    // khv dead after attnf

  // 1. all preprocessing in one launch (box query first — latency-bound)
  CvtArgs ca;
  ca.src[0] = q_w; ca.dst[0] = qwb;
  ca.src[1] = k_w; ca.dst[1] = kvwb;
  ca.src[2] = v_w; ca.dst[2] = kvwb + (size_t)C_ * C_;
  ca.src[3] = o_w; ca.dst[3] = owb;
  ca.src[4] = lin1_w; ca.dst[4] = l1b;
  ca.src[5] = lin2_w; ca.dst[5] = l2b;
  k_prep<<<NPREP, 256, 0, stream>>>(query, key, query_pos, key_pos,
                                    qpe_w, qpe_b, k_w, k_b, v_w, v_b,
                                    kpe_w, kpe_b, ca,
                                    keyTb, qtokb, qinb, Pk, Pv, idxb, maskb);
  // 2. khv = key_feat @ [k_w|v_w]^T  +  qh = qin @ q_w.T + q_b (XCD-swizzled)
  k_gemm2<<<1024 + 128, 256, 0, stream>>>(keyTb, kvwb, khvbuf, qinb, qwb, q_b, qhb);
  // 3. fused attention (wave-parallel softmax)
  k_attnf<<<BQ_, 256, 0, stream>>>(khvbuf, key_pos, query_pos, idxb, maskb,
                                   qhb, Pk, Pv, aob);
  // 4. fused o-proj + residual + LN1 -> x1b (512 thr, v3: 2 blocks/CU)
  k_oln<<<BQ_ / 32, 512, 0, stream>>>(aob, owb, o_b, qtokb, n1_g, n1_b, x1b);
  // 5. ff1(bf16) = relu(x1b @ lin1.T + b)   [overlays khvbuf]
  k_gemm<128, 128, 1, 1><<<dim3(FF_ / 128, BQ_ / 128), 256, 0, stream>>>(
      x1b, l1b, lin1_b, ff1b, FF_, C_);
  // 6. fused ff2 + residual + LN2 + transpose -> out (512 thr, v3: 2 blocks/CU)
  k_ff2lnt<<<BQ_ / 32, 512, 0, stream>>>(ff1b, l2b, lin2_b, x1b, n2_g, n2_b, out);
}